// Round 6
// baseline (85.934 us; speedup 1.0000x reference)
//
#include <hip/hip_runtime.h>
#include <hip/hip_bf16.h>

#define LN_EPS 1e-5f

typedef __attribute__((ext_vector_type(8))) short short8;
typedef __attribute__((ext_vector_type(4))) float floatx4;

static __device__ __forceinline__ unsigned int f2bfu(float f) {
    __hip_bfloat16 h = __float2bfloat16(f);
    return (unsigned int)__builtin_bit_cast(unsigned short, h);
}
static __device__ __forceinline__ float bf2f_lo(unsigned int u) {
    return __builtin_bit_cast(float, (u & 0xffffu) << 16);
}
static __device__ __forceinline__ float bf2f_hi(unsigned int u) {
    return __builtin_bit_cast(float, u & 0xffff0000u);
}

#define TA_P_STRIDE (256 * 512)    // tableA: [16][256][512] bf16
#define T2_P_STRIDE (257 * 1024)   // table2: [16][257][1024] bf16; row 256 = up_b/16

// ---------------------------------------------------------------------------
// k_prep: blocks 0..511 cast up_w -> wb; 512..639 cast byte_emb -> bb;
// 640..655 write table2[p][256][:] = bf16(up_b/16)  (missing-id row; summing
// 16 of them reconstructs +up_b exactly).
// ---------------------------------------------------------------------------
__global__ __launch_bounds__(256) void k_prep(
    const float* __restrict__ up_w, const float* __restrict__ byte_emb,
    const float* __restrict__ up_b,
    unsigned short* __restrict__ wb, unsigned short* __restrict__ bb,
    unsigned short* __restrict__ T2)
{
    const int b = blockIdx.x;
    if (b < 640) {
        const float* src;
        unsigned short* dst;
        int idx;
        if (b < 512) { src = up_w;     dst = wb; idx = (b * 256 + threadIdx.x) * 4; }
        else         { src = byte_emb; dst = bb; idx = ((b - 512) * 256 + threadIdx.x) * 4; }
        const float4 v = *(const float4*)&src[idx];
        ushort4 o;
        o.x = (unsigned short)f2bfu(v.x); o.y = (unsigned short)f2bfu(v.y);
        o.z = (unsigned short)f2bfu(v.z); o.w = (unsigned short)f2bfu(v.w);
        *(ushort4*)&dst[idx] = o;
    } else {
        const int p = b - 640;
        const int d = threadIdx.x * 4;
        const float4 v = *(const float4*)&up_b[d];
        ushort4 o;
        o.x = (unsigned short)f2bfu(v.x * 0.0625f);
        o.y = (unsigned short)f2bfu(v.y * 0.0625f);
        o.z = (unsigned short)f2bfu(v.z * 0.0625f);
        o.w = (unsigned short)f2bfu(v.w * 0.0625f);
        *(ushort4*)&T2[(size_t)p * T2_P_STRIDE + 256 * 1024 + d] = o;
    }
}

// ---------------------------------------------------------------------------
// k1_t: tableA[p][m][j] = sum_i bb[m][i] * pos_emb[p][i][j]   (bf16 MFMA)
// K-step 64, double-buffered LDS transpose of pos_emb, 1 barrier/iter.
// Block 256 thr = 4 waves (2m x 2j); block tile 64m x 64j; grid (8,4,16).
// ---------------------------------------------------------------------------
__global__ __launch_bounds__(256) void k1_t(
    const unsigned short* __restrict__ A,   // bb [256][512] bf16
    const float* __restrict__ P,            // pos_emb [16][512][512] f32
    unsigned short* __restrict__ T)         // tableA [16][256][512] bf16
{
    const int p  = blockIdx.z;
    const int j0 = blockIdx.x * 64;
    const int m0 = blockIdx.y * 64;
    const float* __restrict__ Pp = P + (size_t)p * 512 * 512;
    unsigned short* __restrict__ Tp = T + (size_t)p * TA_P_STRIDE;

    __shared__ unsigned short Bs[2][64][72];   // [j][i], 144B rows

    const int tid  = threadIdx.x;
    const int w    = tid >> 6, lane = tid & 63;
    const int lr   = lane & 15, lg = lane >> 4, lk = lg * 8;
    const int wr   = w >> 1, wc = w & 1;
    const int jq   = tid & 15;              // j quad: j = 4*jq..+3
    const int ip   = tid >> 4;              // i pairs: {2ip,2ip+1}, {2ip+32,2ip+33}

    float4 v0, v1, v2, v3;
    #define LOADP(it) do {                                                    \
        const float* bp = Pp + (size_t)((it) * 64) * 512 + j0 + 4 * jq;       \
        v0 = *(const float4*)&bp[(size_t)(2 * ip)      * 512];                \
        v1 = *(const float4*)&bp[(size_t)(2 * ip + 1)  * 512];                \
        v2 = *(const float4*)&bp[(size_t)(2 * ip + 32) * 512];                \
        v3 = *(const float4*)&bp[(size_t)(2 * ip + 33) * 512];                \
    } while (0)
    #define WRITEB(buf) do {                                                  \
        *(unsigned int*)&Bs[buf][4 * jq + 0][2 * ip]        = f2bfu(v0.x) | (f2bfu(v1.x) << 16); \
        *(unsigned int*)&Bs[buf][4 * jq + 1][2 * ip]        = f2bfu(v0.y) | (f2bfu(v1.y) << 16); \
        *(unsigned int*)&Bs[buf][4 * jq + 2][2 * ip]        = f2bfu(v0.z) | (f2bfu(v1.z) << 16); \
        *(unsigned int*)&Bs[buf][4 * jq + 3][2 * ip]        = f2bfu(v0.w) | (f2bfu(v1.w) << 16); \
        *(unsigned int*)&Bs[buf][4 * jq + 0][2 * (ip + 16)] = f2bfu(v2.x) | (f2bfu(v3.x) << 16); \
        *(unsigned int*)&Bs[buf][4 * jq + 1][2 * (ip + 16)] = f2bfu(v2.y) | (f2bfu(v3.y) << 16); \
        *(unsigned int*)&Bs[buf][4 * jq + 2][2 * (ip + 16)] = f2bfu(v2.z) | (f2bfu(v3.z) << 16); \
        *(unsigned int*)&Bs[buf][4 * jq + 3][2 * (ip + 16)] = f2bfu(v2.w) | (f2bfu(v3.w) << 16); \
    } while (0)

    floatx4 acc[2][2] = {};

    LOADP(0);
    WRITEB(0);
    __syncthreads();

    for (int it = 0; it < 8; ++it) {
        if (it < 7) LOADP(it + 1);
        #pragma unroll
        for (int kf = 0; kf < 2; ++kf) {
            short8 a[2], bfr[2];
            #pragma unroll
            for (int mf = 0; mf < 2; ++mf)
                a[mf] = *(const short8*)&A[(size_t)(m0 + wr * 32 + mf * 16 + lr) * 512
                                           + it * 64 + kf * 32 + lk];
            #pragma unroll
            for (int nf = 0; nf < 2; ++nf)
                bfr[nf] = *(const short8*)&Bs[it & 1][wc * 32 + nf * 16 + lr][kf * 32 + lk];
            #pragma unroll
            for (int mf = 0; mf < 2; ++mf)
                #pragma unroll
                for (int nf = 0; nf < 2; ++nf)
                    acc[mf][nf] = __builtin_amdgcn_mfma_f32_16x16x32_bf16(
                        a[mf], bfr[nf], acc[mf][nf], 0, 0, 0);
        }
        if (it < 7) {
            WRITEB((it + 1) & 1);
            __syncthreads();
        }
    }

    #pragma unroll
    for (int nf = 0; nf < 2; ++nf)
        #pragma unroll
        for (int mf = 0; mf < 2; ++mf)
            #pragma unroll
            for (int q = 0; q < 4; ++q)
                Tp[(size_t)(m0 + wr * 32 + mf * 16 + lg * 4 + q) * 512
                   + j0 + wc * 32 + nf * 16 + lr]
                    = (unsigned short)f2bfu(acc[mf][nf][q]);
    #undef LOADP
    #undef WRITEB
}

// ---------------------------------------------------------------------------
// k_up: table2[p][m][d] = bf16( sum_j tableA[p][m][j]*wb[d][j] + up_b[d]/16 )
// Both operands K-major, L2-resident -> direct-from-global fragments.
// Block 256 thr = 4 waves (2x2), wave tile 32x32, block tile 64x64.
// Grid (16 d-tiles, 4 m-tiles, 16 p) = 1024 blocks.
// ---------------------------------------------------------------------------
__global__ __launch_bounds__(256) void k_up(
    const unsigned short* __restrict__ TA,  // [16][256][512] bf16
    const unsigned short* __restrict__ Wb,  // [1024][512] bf16
    const float* __restrict__ up_b,
    unsigned short* __restrict__ T2)        // [16][257][1024] bf16
{
    const int p  = blockIdx.z;
    const int d0 = blockIdx.x * 64;
    const int m0 = blockIdx.y * 64;
    const unsigned short* __restrict__ Ap = TA + (size_t)p * TA_P_STRIDE;
    unsigned short* __restrict__ Cp = T2 + (size_t)p * T2_P_STRIDE;

    const int tid = threadIdx.x;
    const int w   = tid >> 6, lane = tid & 63;
    const int lr  = lane & 15, lg = lane >> 4, lk = lg * 8;
    const int wr  = w >> 1, wc = w & 1;

    floatx4 acc[2][2] = {};

    for (int k0 = 0; k0 < 512; k0 += 32) {
        short8 a[2], bfr[2];
        #pragma unroll
        for (int mf = 0; mf < 2; ++mf)
            a[mf] = *(const short8*)&Ap[(size_t)(m0 + wr * 32 + mf * 16 + lr) * 512 + k0 + lk];
        #pragma unroll
        for (int nf = 0; nf < 2; ++nf)
            bfr[nf] = *(const short8*)&Wb[(size_t)(d0 + wc * 32 + nf * 16 + lr) * 512 + k0 + lk];
        #pragma unroll
        for (int mf = 0; mf < 2; ++mf)
            #pragma unroll
            for (int nf = 0; nf < 2; ++nf)
                acc[mf][nf] = __builtin_amdgcn_mfma_f32_16x16x32_bf16(
                    a[mf], bfr[nf], acc[mf][nf], 0, 0, 0);
    }

    #pragma unroll
    for (int nf = 0; nf < 2; ++nf) {
        const int col = d0 + wc * 32 + nf * 16 + lr;
        const float ub = up_b[col] * 0.0625f;
        #pragma unroll
        for (int mf = 0; mf < 2; ++mf)
            #pragma unroll
            for (int q = 0; q < 4; ++q)
                Cp[(size_t)(m0 + wr * 32 + mf * 16 + lg * 4 + q) * 1024 + col]
                    = (unsigned short)f2bfu(acc[mf][nf][q] + ub);
    }
}

// ---------------------------------------------------------------------------
// k_out: out[row][d] = LN( sum_p table2[p][idc(row,p)][d] ).
// One wave per row (4 rows/block); lane owns d = lane*16..+15 (32B/lane/p,
// two dwordx4). No LDS, no barriers; 2-stage load pipeline; full-wave shfl LN.
// ---------------------------------------------------------------------------
__global__ __launch_bounds__(256) void k_out(
    const int* __restrict__ ids,            // [rows][16]
    const unsigned short* __restrict__ T2,  // [16][257][1024] bf16
    const float* __restrict__ gamma,
    const float* __restrict__ beta,
    float* __restrict__ out)                // [rows][1024] f32
{
    const int row  = blockIdx.x * 4 + (threadIdx.x >> 6);
    const int lane = threadIdx.x & 63;

    const int4* idp = (const int4*)(ids + row * 16);
    const int4 q0 = idp[0], q1 = idp[1], q2 = idp[2], q3 = idp[3];
    const int idv[16] = {q0.x, q0.y, q0.z, q0.w, q1.x, q1.y, q1.z, q1.w,
                         q2.x, q2.y, q2.z, q2.w, q3.x, q3.y, q3.z, q3.w};

    const size_t lbase = (size_t)lane * 16;
    float acc[16] = {};

    uint4 c0, c1, n0, n1;
    #define TADDR(pp) (&T2[(size_t)((pp) * 257 + (idv[pp] < 0 ? 256 : idv[pp])) * 1024 + lbase])
    {
        const unsigned short* a = TADDR(0);
        c0 = *(const uint4*)a;
        c1 = *(const uint4*)(a + 8);
    }
    #pragma unroll
    for (int p = 0; p < 16; ++p) {
        if (p < 15) {
            const unsigned short* a = TADDR(p + 1);
            n0 = *(const uint4*)a;
            n1 = *(const uint4*)(a + 8);
        }
        acc[0]  += bf2f_lo(c0.x);  acc[1]  += bf2f_hi(c0.x);
        acc[2]  += bf2f_lo(c0.y);  acc[3]  += bf2f_hi(c0.y);
        acc[4]  += bf2f_lo(c0.z);  acc[5]  += bf2f_hi(c0.z);
        acc[6]  += bf2f_lo(c0.w);  acc[7]  += bf2f_hi(c0.w);
        acc[8]  += bf2f_lo(c1.x);  acc[9]  += bf2f_hi(c1.x);
        acc[10] += bf2f_lo(c1.y);  acc[11] += bf2f_hi(c1.y);
        acc[12] += bf2f_lo(c1.z);  acc[13] += bf2f_hi(c1.z);
        acc[14] += bf2f_lo(c1.w);  acc[15] += bf2f_hi(c1.w);
        c0 = n0; c1 = n1;
    }
    #undef TADDR

    float s = 0.0f, ss = 0.0f;
    #pragma unroll
    for (int j = 0; j < 16; ++j) { s += acc[j]; ss += acc[j] * acc[j]; }
    #pragma unroll
    for (int off = 1; off < 64; off <<= 1) {
        s  += __shfl_xor(s,  off, 64);
        ss += __shfl_xor(ss, off, 64);
    }
    const float mu   = s * (1.0f / 1024.0f);
    const float var  = ss * (1.0f / 1024.0f) - mu * mu;
    const float rstd = rsqrtf(var + LN_EPS);

    float* __restrict__ orow = out + (size_t)row * 1024 + lane * 16;
    #pragma unroll
    for (int h = 0; h < 4; ++h) {
        const float4 g  = *(const float4*)&gamma[lane * 16 + h * 4];
        const float4 bt = *(const float4*)&beta [lane * 16 + h * 4];
        float4 o;
        o.x = (acc[h * 4 + 0] - mu) * rstd * g.x + bt.x;
        o.y = (acc[h * 4 + 1] - mu) * rstd * g.y + bt.y;
        o.z = (acc[h * 4 + 2] - mu) * rstd * g.z + bt.z;
        o.w = (acc[h * 4 + 3] - mu) * rstd * g.w + bt.w;
        *(float4*)&orow[h * 4] = o;
    }
}

extern "C" void kernel_launch(void* const* d_in, const int* in_sizes, int n_in,
                              void* d_out, int out_size, void* d_ws, size_t ws_size,
                              hipStream_t stream) {
    const int*   ids      = (const int*)d_in[0];
    const float* byte_emb = (const float*)d_in[1];
    const float* pos_emb  = (const float*)d_in[2];
    const float* up_w     = (const float*)d_in[3];
    const float* up_b     = (const float*)d_in[4];
    const float* gamma    = (const float*)d_in[5];
    const float* beta     = (const float*)d_in[6];
    float* out = (float*)d_out;

    // ws: wb [1024][512] 1MB | bb [256][512] 0.25MB | tableA 4MB | table2 8.42MB
    unsigned short* wb     = (unsigned short*)d_ws;
    unsigned short* bb     = wb + (size_t)1024 * 512;
    unsigned short* tableA = bb + (size_t)256 * 512;
    unsigned short* table2 = tableA + (size_t)16 * TA_P_STRIDE;

    const int rows = in_sizes[0] / 16;   // 8192

    k_prep<<<656, 256, 0, stream>>>(up_w, byte_emb, up_b, wb, bb, table2);

    dim3 g1(8, 4, 16);
    k1_t<<<g1, 256, 0, stream>>>(bb, pos_emb, tableA);

    dim3 g2(16, 4, 16);
    k_up<<<g2, 256, 0, stream>>>(tableA, wb, up_b, table2);

    k_out<<<rows / 4, 256, 0, stream>>>(ids, table2, gamma, beta, out);
}

// Round 7
// 82.407 us; speedup vs baseline: 1.0428x; 1.0428x over previous
//
#include <hip/hip_runtime.h>
#include <hip/hip_bf16.h>

#define LN_EPS 1e-5f

typedef __attribute__((ext_vector_type(8))) short short8;
typedef __attribute__((ext_vector_type(4))) float floatx4;

static __device__ __forceinline__ unsigned int f2bfu(float f) {
    __hip_bfloat16 h = __float2bfloat16(f);
    return (unsigned int)__builtin_bit_cast(unsigned short, h);
}
static __device__ __forceinline__ float bf2f_lo(unsigned int u) {
    return __builtin_bit_cast(float, (u & 0xffffu) << 16);
}
static __device__ __forceinline__ float bf2f_hi(unsigned int u) {
    return __builtin_bit_cast(float, u & 0xffff0000u);
}

#define TA_P_STRIDE (257 * 512)   // tableA: [16][257][512] bf16; row 256 = zeros

// ---------------------------------------------------------------------------
// k_prep: blocks 0..511 cast up_w -> wb; 512..639 cast byte_emb -> bb;
// 640..655 zero tableA's 16 pad rows (missing-id row).
// ---------------------------------------------------------------------------
__global__ __launch_bounds__(256) void k_prep(
    const float* __restrict__ up_w, const float* __restrict__ byte_emb,
    unsigned short* __restrict__ wb, unsigned short* __restrict__ bb,
    unsigned short* __restrict__ T)
{
    const int b = blockIdx.x;
    if (b < 640) {
        const float* src;
        unsigned short* dst;
        int idx;
        if (b < 512) { src = up_w;     dst = wb; idx = (b * 256 + threadIdx.x) * 4; }
        else         { src = byte_emb; dst = bb; idx = ((b - 512) * 256 + threadIdx.x) * 4; }
        const float4 v = *(const float4*)&src[idx];
        ushort4 o;
        o.x = (unsigned short)f2bfu(v.x); o.y = (unsigned short)f2bfu(v.y);
        o.z = (unsigned short)f2bfu(v.z); o.w = (unsigned short)f2bfu(v.w);
        *(ushort4*)&dst[idx] = o;
    } else {
        const int p = b - 640;
        if (threadIdx.x < 128) {
            ushort4 z; z.x = z.y = z.z = z.w = 0;
            *(ushort4*)&T[(size_t)p * TA_P_STRIDE + 256 * 512 + threadIdx.x * 4] = z;
        }
    }
}

// ---------------------------------------------------------------------------
// k_castT: transpose-cast pos_emb [16][512i][512j] f32 -> posT bf16 [p][j][i].
// 64x64 LDS tile, pad 65 (proven in R3). Grid (8,8,16), 256 thr.
// ---------------------------------------------------------------------------
__global__ __launch_bounds__(256) void k_castT(
    const float* __restrict__ P,
    unsigned short* __restrict__ PT)
{
    const int p  = blockIdx.z;
    const int i0 = blockIdx.y * 64;
    const int j0 = blockIdx.x * 64;
    const float* __restrict__ Pp = P + (size_t)p * 512 * 512;
    unsigned short* __restrict__ Tp = PT + (size_t)p * 512 * 512;

    __shared__ float S[64][65];
    const int r  = threadIdx.x >> 2;        // 0..63
    const int c0 = (threadIdx.x & 3) * 16;  // 0,16,32,48

    #pragma unroll
    for (int c = 0; c < 16; c += 4) {
        const float4 v = *(const float4*)&Pp[(size_t)(i0 + r) * 512 + j0 + c0 + c];
        S[r][c0 + c + 0] = v.x;
        S[r][c0 + c + 1] = v.y;
        S[r][c0 + c + 2] = v.z;
        S[r][c0 + c + 3] = v.w;
    }
    __syncthreads();

    #pragma unroll
    for (int h = 0; h < 2; ++h) {
        short8 o;
        #pragma unroll
        for (int k = 0; k < 8; ++k)
            o[k] = (short)f2bfu(S[c0 + h * 8 + k][r]);
        *(short8*)&Tp[(size_t)(j0 + r) * 512 + i0 + c0 + h * 8] = o;
    }
}

// ---------------------------------------------------------------------------
// k1_d: tableA[p][m][j] = sum_i bb[m][i] * posT[p][j][i]  (bf16 MFMA)
// Both operands K-major -> direct-from-global fragments, NO LDS, NO barriers.
// Block 256 thr = 4 waves (2x2), wave tile 32x32. Grid (8,4,16) = 512 blocks.
// ---------------------------------------------------------------------------
__global__ __launch_bounds__(256) void k1_d(
    const unsigned short* __restrict__ A,   // bb [256][512] bf16
    const unsigned short* __restrict__ PT,  // posT [16][512][512] bf16 ([p][j][i])
    unsigned short* __restrict__ T)         // tableA [16][257][512] bf16
{
    const int p  = blockIdx.z;
    const int j0 = blockIdx.x * 64;
    const int m0 = blockIdx.y * 64;
    const unsigned short* __restrict__ Bp = PT + (size_t)p * 512 * 512;
    unsigned short* __restrict__ Tp = T + (size_t)p * TA_P_STRIDE;

    const int tid = threadIdx.x;
    const int w   = tid >> 6, lane = tid & 63;
    const int lr  = lane & 15, lg = lane >> 4, lk = lg * 8;
    const int wr  = w >> 1, wc = w & 1;

    floatx4 acc[2][2] = {};

    #pragma unroll
    for (int k0 = 0; k0 < 512; k0 += 32) {
        short8 a[2], bfr[2];
        #pragma unroll
        for (int mf = 0; mf < 2; ++mf)
            a[mf] = *(const short8*)&A[(size_t)(m0 + wr * 32 + mf * 16 + lr) * 512 + k0 + lk];
        #pragma unroll
        for (int nf = 0; nf < 2; ++nf)
            bfr[nf] = *(const short8*)&Bp[(size_t)(j0 + wc * 32 + nf * 16 + lr) * 512 + k0 + lk];
        #pragma unroll
        for (int mf = 0; mf < 2; ++mf)
            #pragma unroll
            for (int nf = 0; nf < 2; ++nf)
                acc[mf][nf] = __builtin_amdgcn_mfma_f32_16x16x32_bf16(
                    a[mf], bfr[nf], acc[mf][nf], 0, 0, 0);
    }

    #pragma unroll
    for (int nf = 0; nf < 2; ++nf)
        #pragma unroll
        for (int mf = 0; mf < 2; ++mf)
            #pragma unroll
            for (int q = 0; q < 4; ++q)
                Tp[(size_t)(m0 + wr * 32 + mf * 16 + lg * 4 + q) * 512
                   + j0 + wc * 32 + nf * 16 + lr]
                    = (unsigned short)f2bfu(acc[mf][nf][q]);
}

// ---------------------------------------------------------------------------
// k_fused2: gather + up-projection + LayerNorm, ONE gather barrier.
// Block = 32 rows x 1024 cols, 1024 thr (16 waves; wave w -> cols w*64..+63).
// Phase 1: gather-sum the full 32x512 A-tile into LDS (32 independent 16B
//   loads/thread from L2-resident tableA), one barrier.
// Phase 2: barrier-free register GEMM: A-frags from XOR-swizzled LDS,
//   B-frags direct from global up_w, 16 unrolled K-steps x 8 MFMA.
// Epilogue: bias + row-LN (16-lane shfl + cross-wave LDS reduce).
// ---------------------------------------------------------------------------
__global__ __launch_bounds__(1024) void k_fused2(
    const int* __restrict__ ids,            // [rows][16]
    const unsigned short* __restrict__ T,   // tableA [16][257][512] bf16
    const unsigned short* __restrict__ Bw,  // up_w [1024][512] bf16
    const float* __restrict__ up_b,
    const float* __restrict__ gamma,
    const float* __restrict__ beta,
    float* __restrict__ out)                // [rows][1024] f32
{
    const int r0   = blockIdx.x * 32;
    const int tid  = threadIdx.x;
    const int w    = tid >> 6, lane = tid & 63;
    const int lr   = lane & 15, lg = lane >> 4, lk = lg * 8;
    const int colb = w * 64;

    __shared__ unsigned short A_lds[32 * 512];   // 32 KB, 1024B rows, XOR-swizzled
    __shared__ int   ids_s[512];
    __shared__ float redS[32][17], redQ[32][17];

    if (tid < 512) ids_s[tid] = ids[r0 * 16 + tid];
    __syncthreads();

    // ---- phase 1: gather-sum into A_lds (row grow, two 8-short slots)
    {
        const int grow = tid >> 5, gq = tid & 31;
        unsigned int goff[16];
        #pragma unroll
        for (int p = 0; p < 16; ++p) {
            const int id = ids_s[grow * 16 + p];
            goff[p] = (unsigned int)((p * 257 + (id < 0 ? 256 : id)) * 512);
        }
        float a0[8] = {}, a1[8] = {};
        #pragma unroll
        for (int p = 0; p < 16; ++p) {
            const uint4 u0 = *(const uint4*)&T[goff[p] + gq * 8];
            const uint4 u1 = *(const uint4*)&T[goff[p] + (gq + 32) * 8];
            a0[0] += bf2f_lo(u0.x); a0[1] += bf2f_hi(u0.x);
            a0[2] += bf2f_lo(u0.y); a0[3] += bf2f_hi(u0.y);
            a0[4] += bf2f_lo(u0.z); a0[5] += bf2f_hi(u0.z);
            a0[6] += bf2f_lo(u0.w); a0[7] += bf2f_hi(u0.w);
            a1[0] += bf2f_lo(u1.x); a1[1] += bf2f_hi(u1.x);
            a1[2] += bf2f_lo(u1.y); a1[3] += bf2f_hi(u1.y);
            a1[4] += bf2f_lo(u1.z); a1[5] += bf2f_hi(u1.z);
            a1[6] += bf2f_lo(u1.w); a1[7] += bf2f_hi(u1.w);
        }
        uint4 o0, o1;
        o0.x = f2bfu(a0[0]) | (f2bfu(a0[1]) << 16);
        o0.y = f2bfu(a0[2]) | (f2bfu(a0[3]) << 16);
        o0.z = f2bfu(a0[4]) | (f2bfu(a0[5]) << 16);
        o0.w = f2bfu(a0[6]) | (f2bfu(a0[7]) << 16);
        o1.x = f2bfu(a1[0]) | (f2bfu(a1[1]) << 16);
        o1.y = f2bfu(a1[2]) | (f2bfu(a1[3]) << 16);
        o1.z = f2bfu(a1[4]) | (f2bfu(a1[5]) << 16);
        o1.w = f2bfu(a1[6]) | (f2bfu(a1[7]) << 16);
        const unsigned int m = (unsigned int)((grow & 7) << 4);
        *(uint4*)((char*)A_lds + ((((unsigned)grow << 10) + ((unsigned)gq << 4)) ^ m)) = o0;
        *(uint4*)((char*)A_lds + ((((unsigned)grow << 10) + ((unsigned)(gq + 32) << 4)) ^ m)) = o1;
    }
    __syncthreads();

    // ---- phase 2: barrier-free register GEMM
    floatx4 acc[2][4] = {};
    #pragma unroll
    for (int it = 0; it < 16; ++it) {        // K-step 32
        short8 a[2], bfr[4];
        #pragma unroll
        for (int mf = 0; mf < 2; ++mf) {
            const int row = mf * 16 + lr;
            const unsigned int byt =
                (((unsigned)row << 10) + (unsigned)((it * 32 + lk) * 2))
                ^ (unsigned)((row & 7) << 4);
            a[mf] = *(const short8*)((const char*)A_lds + byt);
        }
        #pragma unroll
        for (int nf = 0; nf < 4; ++nf)
            bfr[nf] = *(const short8*)&Bw[(size_t)(colb + nf * 16 + lr) * 512
                                          + it * 32 + lk];
        #pragma unroll
        for (int mf = 0; mf < 2; ++mf)
            #pragma unroll
            for (int nf = 0; nf < 4; ++nf)
                acc[mf][nf] = __builtin_amdgcn_mfma_f32_16x16x32_bf16(
                    a[mf], bfr[nf], acc[mf][nf], 0, 0, 0);
    }

    // ---- epilogue: bias + LayerNorm
    #pragma unroll
    for (int nf = 0; nf < 4; ++nf) {
        const float bias = up_b[colb + nf * 16 + lr];
        #pragma unroll
        for (int mf = 0; mf < 2; ++mf)
            #pragma unroll
            for (int q = 0; q < 4; ++q)
                acc[mf][nf][q] += bias;
    }

    float s[2][4], ss[2][4];
    #pragma unroll
    for (int mf = 0; mf < 2; ++mf)
        #pragma unroll
        for (int q = 0; q < 4; ++q) {
            float t1 = 0.0f, t2 = 0.0f;
            #pragma unroll
            for (int nf = 0; nf < 4; ++nf) {
                const float v = acc[mf][nf][q];
                t1 += v; t2 += v * v;
            }
            #pragma unroll
            for (int off = 1; off < 16; off <<= 1) {
                t1 += __shfl_xor(t1, off, 16);
                t2 += __shfl_xor(t2, off, 16);
            }
            s[mf][q] = t1; ss[mf][q] = t2;
        }

    if (lr == 0) {
        #pragma unroll
        for (int mf = 0; mf < 2; ++mf)
            #pragma unroll
            for (int q = 0; q < 4; ++q) {
                const int row = mf * 16 + lg * 4 + q;
                redS[row][w] = s[mf][q];
                redQ[row][w] = ss[mf][q];
            }
    }
    __syncthreads();

    float mu[2][4], rs[2][4];
    #pragma unroll
    for (int mf = 0; mf < 2; ++mf)
        #pragma unroll
        for (int q = 0; q < 4; ++q) {
            const int row = mf * 16 + lg * 4 + q;
            float S = 0.0f, SS = 0.0f;
            #pragma unroll
            for (int ww = 0; ww < 16; ++ww) { S += redS[row][ww]; SS += redQ[row][ww]; }
            const float m  = S * (1.0f / 1024.0f);
            const float vr = SS * (1.0f / 1024.0f) - m * m;
            mu[mf][q] = m;
            rs[mf][q] = rsqrtf(vr + LN_EPS);
        }

    #pragma unroll
    for (int nf = 0; nf < 4; ++nf) {
        const int col = colb + nf * 16 + lr;
        const float g  = gamma[col];
        const float be = beta[col];
        #pragma unroll
        for (int mf = 0; mf < 2; ++mf)
            #pragma unroll
            for (int q = 0; q < 4; ++q) {
                const int row = mf * 16 + lg * 4 + q;
                out[(size_t)(r0 + row) * 1024 + col]
                    = (acc[mf][nf][q] - mu[mf][q]) * rs[mf][q] * g + be;
            }
    }
}

extern "C" void kernel_launch(void* const* d_in, const int* in_sizes, int n_in,
                              void* d_out, int out_size, void* d_ws, size_t ws_size,
                              hipStream_t stream) {
    const int*   ids      = (const int*)d_in[0];
    const float* byte_emb = (const float*)d_in[1];
    const float* pos_emb  = (const float*)d_in[2];
    const float* up_w     = (const float*)d_in[3];
    const float* up_b     = (const float*)d_in[4];
    const float* gamma    = (const float*)d_in[5];
    const float* beta     = (const float*)d_in[6];
    float* out = (float*)d_out;

    // ws: wb [1024][512] 1MB | bb [256][512] 0.25MB | posT 8MB | tableA ~4.2MB
    unsigned short* wb     = (unsigned short*)d_ws;
    unsigned short* bb     = wb + (size_t)1024 * 512;
    unsigned short* posT   = bb + (size_t)256 * 512;
    unsigned short* tableA = posT + (size_t)16 * 512 * 512;

    const int rows = in_sizes[0] / 16;   // 8192

    k_prep<<<656, 256, 0, stream>>>(up_w, byte_emb, wb, bb, tableA);

    dim3 gt(8, 8, 16);
    k_castT<<<gt, 256, 0, stream>>>(pos_emb, posT);

    dim3 g1(8, 4, 16);
    k1_d<<<g1, 256, 0, stream>>>(bb, posT, tableA);

    k_fused2<<<rows / 32, 1024, 0, stream>>>(ids, tableA, wb, up_b, gamma, beta, out);
}